// Round 2
// baseline (342.305 us; speedup 1.0000x reference)
//
#include <hip/hip_runtime.h>
#include <math.h>

#define B_SZ   32
#define C_DIM  384
#define H_IN   28
#define W_IN   28
#define TQ     785   // 1 + 28*28
#define TKV    197   // 1 + 14*14
#define NH     6
#define HD     64
#define SCALE_F 0.05103103630798287f       // 384^-0.5
#define SCALE_L2E (0.05103103630798287f * 1.4426950408889634f)  // fold log2(e)
#define BN_EPS_F 1e-5f

#define QROWS    25120        // B_SZ*TQ
#define KVROWS   6304         // B_SZ*TKV
#define QROWS_P  25344        // 66*384 (pad to BM=384)
#define KVROWS_P 6528         // 17*384
#define WELEM    147456       // 384*384
#define VT_LD    208          // V^T key stride (16B-aligned rows, >= 197)

#define QT384    66           // 384-row M-tiles for Q rows
#define KVT384   17           // 384-row M-tiles for K/V rows

typedef _Float16 f16;
typedef f16  f16x8 __attribute__((ext_vector_type(8)));
typedef f16  f16x4 __attribute__((ext_vector_type(4)));
typedef float f32x4 __attribute__((ext_vector_type(4)));

__device__ __forceinline__ void split16(float v, f16& h, f16& l) {
    h = (f16)v;
    l = (f16)(v - (float)h);
}

// async global->LDS DMA, 16 B per lane. HW writes at wave-uniform base +
// lane*16 -- every call site computes LDS offset == uniform + lane*16 B.
__device__ __forceinline__ void cp16(void* lds, const void* g) {
    __builtin_amdgcn_global_load_lds(
        (const __attribute__((address_space(1))) unsigned int*)g,
        (__attribute__((address_space(3))) unsigned int*)lds, 16, 0, 0);
}

// XCD-sibling swizzle: 16-block groups; the 2 n0-siblings of one y-tile sit at
// ids {g*16+xcd, +8} -> same XCD under round-robin id%8 placement, so the
// shared A-panel is L2-local. Returns false for pad blocks.
__device__ __forceinline__ bool swz(int id, int yMax, int& y, int& n0) {
    int g = id / 16, w = id - g * 16;
    y = g * 8 + (w & 7);
    n0 = (w >> 3) * 192;
    return y < yMax;
}

// ---------------- prep: weight decompose (+scale fold into w_q) + conv/BN fold --
__global__ __launch_bounds__(256) void prep_kernel(
    const float* __restrict__ wq, const float* __restrict__ wk,
    const float* __restrict__ wv, const float* __restrict__ wp,
    const float* __restrict__ conv_w,
    const float* __restrict__ gamma, const float* __restrict__ beta,
    const float* __restrict__ mean, const float* __restrict__ var,
    f16* __restrict__ Wh, f16* __restrict__ Wl,
    float* __restrict__ wAll)
{
    int idx = blockIdx.x * 256 + threadIdx.x;
    if (idx < 4 * WELEM) {
        int which = idx / WELEM, rem = idx - which * WELEM;
        const float* s = (which == 0) ? wq : (which == 1) ? wk : (which == 2) ? wv : wp;
        float v = s[rem];
        if (which == 0) v *= SCALE_L2E;   // QK^T logits in log2 domain
        f16 h, l;
        split16(v, h, l);
        Wh[idx] = h; Wl[idx] = l;
    } else if (idx < 4 * WELEM + 3 * C_DIM) {
        int k = idx - 4 * WELEM;
        int cv = k / C_DIM, c = k - cv * C_DIM;
        float inv = gamma[k] * rsqrtf(var[k] + BN_EPS_F);
#pragma unroll
        for (int t = 0; t < 9; ++t)
            wAll[cv * 3840 + t * C_DIM + c] = conv_w[(size_t)cv * C_DIM * 9 + c * 9 + t] * inv;
        wAll[cv * 3840 + 9 * C_DIM + c] = beta[k] - mean[k] * inv;
    }
}

// ---------------- fused depthwise conv (Q stride1 + K/V stride2) + cls row -----
__global__ __launch_bounds__(256) void fused_conv_kernel(
    const float* __restrict__ x,
    const float* __restrict__ wAll,
    f16* __restrict__ qh, f16* __restrict__ ql,
    f16* __restrict__ kh, f16* __restrict__ kl,
    f16* __restrict__ vh, f16* __restrict__ vl)
{
    __shared__ float sW[3 * 3840];
    int tid = threadIdx.x;
    int oi = blockIdx.x, b = blockIdx.y;

    if (oi == H_IN) {                 // cls-token path
        if (tid < 96) {
            int c = tid * 4;
            float4 v = *(const float4*)&x[(size_t)b * TQ * C_DIM + c];
            float a[4] = {v.x, v.y, v.z, v.w};
            f16x4 hv, lv;
#pragma unroll
            for (int u = 0; u < 4; ++u) { f16 h, l; split16(a[u], h, l); hv[u] = h; lv[u] = l; }
            size_t oq = (size_t)b * TQ * C_DIM + c;
            size_t okv = (size_t)b * TKV * C_DIM + c;
            *(f16x4*)&qh[oq] = hv;  *(f16x4*)&ql[oq] = lv;
            *(f16x4*)&kh[okv] = hv; *(f16x4*)&kl[okv] = lv;
            *(f16x4*)&vh[okv] = hv; *(f16x4*)&vl[okv] = lv;
        }
        return;
    }

#pragma unroll
    for (int i = 0; i < 12; ++i) {
        int idx = tid + 256 * i;
        if (idx < 2880) cp16(&sW[idx * 4], &wAll[idx * 4]);
    }
    __syncthreads();

    const size_t xb = (size_t)b * TQ * C_DIM + C_DIM;
    bool oi_even = (oi & 1) == 0;

    for (int it = 0; it < 11; ++it) {
        int idx = tid + 256 * it;
        if (idx >= 28 * 96) break;
        int oj = idx / 96, cg = idx - oj * 96;
        int c = cg * 4;

        float4 xv[9];
#pragma unroll
        for (int di = 0; di < 3; ++di) {
            int ii = oi + di - 1;
            bool rok = (ii >= 0) && (ii < H_IN);
#pragma unroll
            for (int dj = 0; dj < 3; ++dj) {
                int jj = oj + dj - 1;
                bool ok = rok && (jj >= 0) && (jj < W_IN);
                xv[di * 3 + dj] = ok ? *(const float4*)&x[xb + ((size_t)ii * W_IN + jj) * C_DIM + c]
                                     : make_float4(0.f, 0.f, 0.f, 0.f);
            }
        }

        {
            float4 acc = *(const float4*)&sW[0 * 3840 + 9 * C_DIM + c];
#pragma unroll
            for (int t = 0; t < 9; ++t) {
                float4 w4 = *(const float4*)&sW[0 * 3840 + t * C_DIM + c];
                acc.x += w4.x * xv[t].x; acc.y += w4.y * xv[t].y;
                acc.z += w4.z * xv[t].z; acc.w += w4.w * xv[t].w;
            }
            f16x4 hv, lv;
            float a[4] = {acc.x, acc.y, acc.z, acc.w};
#pragma unroll
            for (int u = 0; u < 4; ++u) { f16 h, l; split16(a[u], h, l); hv[u] = h; lv[u] = l; }
            size_t off = ((size_t)b * TQ + 1 + oi * W_IN + oj) * C_DIM + c;
            *(f16x4*)&qh[off] = hv;
            *(f16x4*)&ql[off] = lv;
        }

        if (oi_even && ((oj & 1) == 0)) {
            int p = (oi >> 1) * 14 + (oj >> 1);
            size_t off = ((size_t)b * TKV + 1 + p) * C_DIM + c;
#pragma unroll
            for (int cv = 1; cv <= 2; ++cv) {
                float4 acc = *(const float4*)&sW[cv * 3840 + 9 * C_DIM + c];
#pragma unroll
                for (int t = 0; t < 9; ++t) {
                    float4 w4 = *(const float4*)&sW[cv * 3840 + t * C_DIM + c];
                    acc.x += w4.x * xv[t].x; acc.y += w4.y * xv[t].y;
                    acc.z += w4.z * xv[t].z; acc.w += w4.w * xv[t].w;
                }
                f16x4 hv, lv;
                float a[4] = {acc.x, acc.y, acc.z, acc.w};
#pragma unroll
                for (int u = 0; u < 4; ++u) { f16 h, l; split16(a[u], h, l); hv[u] = h; lv[u] = l; }
                if (cv == 1) { *(f16x4*)&kh[off] = hv; *(f16x4*)&kl[off] = lv; }
                else         { *(f16x4*)&vh[off] = hv; *(f16x4*)&vl[off] = lv; }
            }
        }
    }
}

// ---------------- split-f16 MFMA GEMM body v3 ---------------------------------
// 384x192 tile, BK=32, 512 threads (8 waves, per-wave 96x96), double-buffered
// LDS (144 KB), one raw barrier + vmcnt(0) per K-step (m97 structure), T2 chunk
// swizzle (source-side pre-swizzle, linear DMA dest), setprio on MFMA cluster.
// Per-buffer layout (f16 units, stride 36864): A_h [0,12288) 384x32,
// A_l [12288,24576), B_h [24576,30720) 192x32, B_l [30720,36864).
// Staging: 72 spans of 1 KB per buffer; span m = c*8 + wv (c=0..8) so each
// call's region is wave-uniform (c=7 straddles B_h/B_l -> p7 select).
__device__ __forceinline__ void gemm_body(
    const f16* __restrict__ Ah, const f16* __restrict__ Al,
    const f16* __restrict__ Wh, const f16* __restrict__ Wl,
    const float* __restrict__ bias,
    float* __restrict__ Cf, f16* __restrict__ Coh, f16* __restrict__ Col,
    int M, int mode, int m0, int n0)
{
    __shared__ f16 lds[2 * 36864];    // 147456 B -> 1 block/CU (8 waves)

    const int t = threadIdx.x;
    const int wv = t >> 6, lane = t & 63;
    const int wr = (wv >> 1) * 96;    // wave M offset (4 positions)
    const int wc = (wv & 1) * 96;     // wave N offset (2 positions)
    const int lrow = lane & 15, quad = lane >> 4;
    const int qsw = quad ^ ((lrow >> 1) & 3);   // T2 read-side chunk swizzle

    // staging geometry: span m = c*8+wv; lane covers row m*16+(lane>>2),
    // global chunk (lane&3)^((lane>>3)&3) (inverse of read-side qsw).
    const int sr16 = wv * 16 + (lane >> 2);
    const int gch  = (lane & 3) ^ ((lane >> 3) & 3);

    const f16* pAh = Ah + (size_t)(m0 + sr16) * 384 + gch * 8;
    const f16* pAl = Al + (size_t)(m0 + sr16) * 384 + gch * 8;
    const f16* pBh = Wh + (size_t)(n0 + sr16) * 384 + gch * 8;
    const f16* pBl = Wl + (size_t)(n0 + sr16) * 384 + gch * 8;
    const f16* p7  = (wv < 4) ? (pBh + 128 * 384) : (pBl - 64 * 384);

#define STAGE(buf, kk) do {                                   \
        f16* db = lds + (buf) * 36864 + wv * 512 + lane * 8;  \
        const int ko = (kk) * 32;                             \
        cp16(db,          pAh + ko);                          \
        cp16(db + 4096,   pAh + 128 * 384 + ko);              \
        cp16(db + 8192,   pAh + 256 * 384 + ko);              \
        cp16(db + 12288,  pAl + ko);                          \
        cp16(db + 16384,  pAl + 128 * 384 + ko);              \
        cp16(db + 20480,  pAl + 256 * 384 + ko);              \
        cp16(db + 24576,  pBh + ko);                          \
        cp16(db + 28672,  p7 + ko);                           \
        cp16(db + 32768,  pBl + 64 * 384 + ko);               \
    } while (0)

    f32x4 acc[6][6];
#pragma unroll
    for (int i = 0; i < 6; ++i)
#pragma unroll
        for (int j = 0; j < 6; ++j)
            acc[i][j] = (f32x4){0.f, 0.f, 0.f, 0.f};

    STAGE(0, 0);

#pragma unroll 2
    for (int kk = 0; kk < 12; ++kk) {
        asm volatile("s_waitcnt vmcnt(0)" ::: "memory");
        __builtin_amdgcn_s_barrier();
        __builtin_amdgcn_sched_barrier(0);
        if (kk < 11) STAGE((kk + 1) & 1, kk + 1);

        const f16* bp = lds + (kk & 1) * 36864;
        __builtin_amdgcn_s_setprio(1);
#pragma unroll
        for (int jh = 0; jh < 2; ++jh) {
            f16x8 bh[3], bl[3];
#pragma unroll
            for (int j3 = 0; j3 < 3; ++j3) {
                int ro = (wc + (jh * 3 + j3) * 16 + lrow) * 32 + qsw * 8;
                bh[j3] = *(const f16x8*)&bp[24576 + ro];
                bl[j3] = *(const f16x8*)&bp[30720 + ro];
            }
#pragma unroll
            for (int i = 0; i < 6; ++i) {
                int ro = (wr + i * 16 + lrow) * 32 + qsw * 8;
                f16x8 ah = *(const f16x8*)&bp[ro];
                f16x8 al = *(const f16x8*)&bp[12288 + ro];
#pragma unroll
                for (int j3 = 0; j3 < 3; ++j3) {
                    int j = jh * 3 + j3;
                    acc[i][j] = __builtin_amdgcn_mfma_f32_16x16x32_f16(ah, bh[j3], acc[i][j], 0, 0, 0);
                    acc[i][j] = __builtin_amdgcn_mfma_f32_16x16x32_f16(ah, bl[j3], acc[i][j], 0, 0, 0);
                    acc[i][j] = __builtin_amdgcn_mfma_f32_16x16x32_f16(al, bh[j3], acc[i][j], 0, 0, 0);
                }
            }
        }
        __builtin_amdgcn_s_setprio(0);
    }
#undef STAGE

    // epilogue: C/D layout col=lane&15, row=quad*4+reg
#pragma unroll
    for (int i = 0; i < 6; ++i) {
        int grow0 = m0 + wr + i * 16 + quad * 4;
#pragma unroll
        for (int j = 0; j < 6; ++j) {
            int gcol = n0 + wc + j * 16 + lrow;
            float bb = (bias && mode == 0) ? bias[gcol] : 0.f;
#pragma unroll
            for (int r = 0; r < 4; ++r) {
                int grow = grow0 + r;
                if (grow >= M) continue;
                float v = acc[i][j][r] + bb;
                if (mode == 0) {
                    Cf[(size_t)grow * 384 + gcol] = v;
                } else if (mode == 1) {
                    f16 h, l;
                    split16(v, h, l);
                    Coh[(size_t)grow * 384 + gcol] = h;
                    Col[(size_t)grow * 384 + gcol] = l;
                } else {
                    int bb2 = grow / TKV;
                    int key = grow - bb2 * TKV;
                    size_t off = (size_t)bb2 * 384 * VT_LD + (size_t)gcol * VT_LD + key;
                    f16 h, l;
                    split16(v, h, l);
                    Coh[off] = h;
                    Col[off] = l;
                }
            }
        }
    }
}

// Q/K/V projections, swizzled 1-D grid. y in [0,66) Q, [66,83) K, [83,100) V.
__global__ __launch_bounds__(512, 2) void qkv_proj_kernel(
    const f16* __restrict__ qh, const f16* __restrict__ ql,
    const f16* __restrict__ kh, const f16* __restrict__ kl,
    const f16* __restrict__ vh, const f16* __restrict__ vl,
    const f16* __restrict__ Wh, const f16* __restrict__ Wl,
    f16* __restrict__ Qph, f16* __restrict__ Qpl,
    f16* __restrict__ Kph, f16* __restrict__ Kpl,
    f16* __restrict__ VTh, f16* __restrict__ VTl,
    int yMax)
{
    int y, n0;
    if (!swz(blockIdx.x, yMax, y, n0)) return;
    if (y < QT384)
        gemm_body(qh, ql, Wh, Wl, nullptr, nullptr, Qph, Qpl, QROWS, 1, y * 384, n0);
    else if (y < QT384 + KVT384)
        gemm_body(kh, kl, Wh + WELEM, Wl + WELEM, nullptr, nullptr, Kph, Kpl,
                  KVROWS, 1, (y - QT384) * 384, n0);
    else
        gemm_body(vh, vl, Wh + 2 * WELEM, Wl + 2 * WELEM, nullptr, nullptr, VTh, VTl,
                  KVROWS, 2, (y - QT384 - KVT384) * 384, n0);
}

// fallback V projection (aliased-VT workspace layout), swizzled
__global__ __launch_bounds__(512, 2) void v_proj_kernel(
    const f16* __restrict__ vh, const f16* __restrict__ vl,
    const f16* __restrict__ Wh, const f16* __restrict__ Wl,
    f16* __restrict__ VTh, f16* __restrict__ VTl)
{
    int y, n0;
    if (!swz(blockIdx.x, KVT384, y, n0)) return;
    gemm_body(vh, vl, Wh, Wl, nullptr, nullptr, VTh, VTl, KVROWS, 2, y * 384, n0);
}

__global__ __launch_bounds__(512, 2) void out_proj_kernel(
    const f16* __restrict__ Ah, const f16* __restrict__ Al,
    const f16* __restrict__ Wh, const f16* __restrict__ Wl,
    const float* __restrict__ bias, float* __restrict__ Cf)
{
    int y, n0;
    if (!swz(blockIdx.x, QT384, y, n0)) return;
    gemm_body(Ah, Al, Wh, Wl, bias, Cf, nullptr, nullptr, QROWS, 0, y * 384, n0);
}

// ---------------- MFMA attention v5: counted-vmcnt pipeline ---------------------
// Raw s_barrier + counted vmcnt everywhere (no full drains). Q in registers.
// LDS: pool = 3 regions x 8192 f16 (R2=Q @0, R0 @8192, R1 @16384) + sPs.
// K tiles: 0->R0 1->R1 2->R0 3->R2 (K2/K3 issued after kt=1's barrier).
// VT tiles: 0->R0 1->R1 2->R2 (issued before softmax), 3->R0 (after PV0).
// T2 chunk swizzle on all f16 tiles. kt=3: j=0 only; vt=3: ks=0 only (rest masked).
__global__ __launch_bounds__(256) void attn_mfma5(
    const f16* __restrict__ Qh, const f16* __restrict__ Ql,
    const f16* __restrict__ Kh, const f16* __restrict__ Kl,
    const f16* __restrict__ VTh, const f16* __restrict__ VTl,
    f16* __restrict__ Oh, f16* __restrict__ Ol)
{
    __shared__ f16 pool[3 * 8192];      // 48 KB
    __shared__ float sPs[64][68];       // 17 KB -> total 66.5 KB, 2 blocks/CU

    const int t = threadIdx.x;
    const int wv = t >> 6, lane = t & 63;
    const int c = lane & 15, quad = lane >> 4;
    const int wq0 = wv * 16;
    const int h = blockIdx.y, b = blockIdx.z;
    const int q0 = blockIdx.x * 64;
    const int qsw_a = quad ^ ((c >> 1) & 3);

    const int R2 = 0, R0 = 8192, R1 = 16384;

    const size_t qbase  = (size_t)b * TQ * C_DIM + h * HD;
    const size_t kbase  = (size_t)b * TKV * C_DIM + h * HD;
    const size_t vtbase = (size_t)b * 384 * VT_LD + (size_t)h * HD * VT_LD;

    // staging: per tile 4 cp16/thread; lane covers row wv*16+(lane>>2),
    // source chunk pre-swizzled with (lane>>3)&3.
    const int srow = wv * 16 + (lane >> 2);
    const int gch  = (lane & 3) ^ ((lane >> 3) & 3);
    const int ldst = wv * 512 + lane * 8;         // f16 units

    const size_t qg = qbase + (size_t)(q0 + srow) * C_DIM + gch * 8;
    const size_t kg = kbase + (size_t)srow * C_DIM + gch * 8;
    const size_t vg = vtbase + (size_t)srow * VT_LD + gch * 8;

#define K_ISSUE(R, KT) do {                                          \
        size_t o_ = kg + (size_t)(KT) * 64 * C_DIM;                  \
        cp16(pool + (R) + ldst,        &Kh[o_]);                     \
        cp16(pool + (R) + 2048 + ldst, &Kh[o_ + 32]);                \
        cp16(pool + (R) + 4096 + ldst, &Kl[o_]);                     \
        cp16(pool + (R) + 6144 + ldst, &Kl[o_ + 32]);                \
    } while (0)

#define VT_ISSUE(R, VT) do {                                         \
        size_t o_ = vg + (VT) * 64;                                  \
        cp16(pool + (R) + ldst,        &VTh[o_]);                    \
        cp16(pool + (R) + 2048 + ldst, &VTh[o_ + 32]);               \
        cp16(pool + (R) + 4096 + ldst, &VTl[o_]);                    \
        cp16(pool + (R) + 6144 + ldst, &VTl[o_ + 32]);               \
    } while (0)

#define WAIT_VM(N)  asm volatile("s_waitcnt vmcnt(" #N ")" ::: "memory")
#define WAIT_VMLG(N) asm volatile("s_waitcnt vmcnt(" #N ") lgkmcnt(0)" ::: "memory")
#define WAIT_LG()   asm volatile("s_waitcnt lgkmcnt(0)" ::: "memory")
#define BAR() do { __builtin_amdgcn_s_barrier(); __builtin_amdgcn_sched_barrier(0); } while (0)

    f32x4 s[4][4];
#pragma unroll
    for (int kt = 0; kt < 4; ++kt)
#pragma unroll
        for (int j = 0; j < 4; ++j)
            s[kt][j] = (f32x4){0.f, 0.f, 0.f, 0.f};

    // prologue: Q -> R2, K0 -> R0, K1 -> R1
    {
        cp16(pool + R2 + ldst,        &Qh[qg]);
        cp16(pool + R2 + 2048 + ldst, &Qh[qg + 32]);
        cp16(pool + R2 + 4096 + ldst, &Ql[qg]);
        cp16(pool + R2 + 6144 + ldst, &Ql[qg + 32]);
    }
    K_ISSUE(R0, 0);
    K_ISSUE(R1, 1);

    f16x8 q8h[2], q8l[2];

#define QK_TILE(KT, R, JMAX) do {                                              \
        __builtin_amdgcn_s_setprio(1);                                         \
        _Pragma("unroll") for (int ks = 0; ks < 2; ++ks) {                     \
            _Pragma("unroll") for (int j = 0; j < (JMAX); ++j) {               \
                int ro = (R) + ks * 2048 + (j * 16 + c) * 32 + qsw_a * 8;      \
                f16x8 kh8 = *(const f16x8*)&pool[ro];                          \
                f16x8 kl8 = *(const f16x8*)&pool[ro + 4096];                   \
                s[KT][j] = __builtin_amdgcn_mfma_f32_16x16x32_f16(q8h[ks], kh8, s[KT][j], 0, 0, 0); \
                s[KT][j] = __builtin_amdgcn_mfma_f32_16x16x32_f16(q8h[ks], kl8, s[KT][j], 0, 0, 0); \
                s[KT][j] = __builtin_amdgcn_mfma_f32_16x16x32_f16(q8l[ks], kh8, s[KT][j], 0, 0, 0); \
            } }                                                                \
        __builtin_amdgcn_s_setprio(0);                                         \
    } while (0)

    // kt = 0 (Q + K0 ready; K1 in flight)
    WAIT_VM(4); BAR();
#pragma unroll
    for (int ks = 0; ks < 2; ++ks) {
        int ro = R2 + ks * 2048 + (wq0 + c) * 32 + qsw_a * 8;
        q8h[ks] = *(const f16x8*)&pool[ro];
        q8l[ks] = *(const f16x8*)&pool[ro + 4096];
    }
    QK_TILE(0, R0, 4);

    // kt = 1
    WAIT_VM(0); BAR();
    K_ISSUE(R0, 2);          // R0's kt=0 reads done (barrier above)
    K_ISSUE(R2, 3);          // Q regs loaded before the barrier
    QK_TILE(1, R1, 4);

    // kt = 2
    WAIT_VM(4); BAR();
    QK_TILE(2, R0, 4);

    // kt = 3 (masked tile: only j=0 holds live keys 192..196)
    WAIT_VM(0); BAR();
    QK_TILE(3, R2, 1);

    // all QK LDS reads done -> regions free for V
    WAIT_LG(); BAR();
    VT_ISSUE(R0, 0);
    VT_ISSUE(R1, 1);
    VT_ISSUE(R2, 2);

    // masking + softmax (rides over VT DMA)
#pragma unroll
    for (int r = 0; r < 4; ++r) {
        s[3][0][r] = (c < 5) ? s[3][0][r] : -1e30f;
        s[3][1][r] = -1e30f;
        s[3][2][r] = -1e30f;
        s[3][3][r] = -1e30f;
    }

    float inv_r[4];
#pragma unroll
    for (int r = 0; r < 4; ++r) {
        float mx = -1e30f;
#pragma unroll
        for (int kt = 0; kt < 4; ++kt)
#pragma unroll
            for (int j = 0; j < 4; ++j)
                mx = fmaxf(mx, s[kt][j][r]);
        mx = fmaxf(mx, __shfl_xor(mx, 1));
        mx = fmaxf(mx, __shfl_xor(mx, 2));
        mx = fmaxf(mx, __shfl_xor(mx, 4));
        mx = fmaxf(mx, __shfl_xor(mx, 8));
        float sum = 0.f;
#pragma unroll
        for (int kt = 0; kt < 4; ++kt)
#pragma unroll
            for (int j = 0; j < 4; ++j) {
                float pv = exp2f(s[kt][j][r] - mx);
                s[kt][j][r] = pv;
                sum += pv;
            }
        sum += __shfl_xor(sum, 1);
        sum += __shfl_xor(sum, 2);
        sum += __shfl_xor(sum, 4);
        sum += __shfl_xor(sum, 8);
        inv_r[r] = 1.f / sum;
    }

    f32x4 o[4];
#pragma unroll
    for (int j = 0; j < 4; ++j) o[j] = (f32x4){0.f, 0.f, 0.f, 0.f};

#define SPS_WRITE(VT) do {                                           \
        _Pragma("unroll") for (int r = 0; r < 4; ++r)                \
            _Pragma("unroll") for (int j = 0; j < 4; ++j)            \
                sPs[wq0 + quad * 4 + r][j * 16 + c] = s[VT][j][r];   \
    } while (0)

#define PV_TILE(R, KSMAX) do {                                                 \
        _Pragma("unroll") for (int ks = 0; ks < (KSMAX); ++ks) {               \
            float4 p0 = *(const float4*)&sPs[wq0 + c][ks * 32 + quad * 8];     \
            float4 p1 = *(const float4*)&sPs[wq0 + c][ks * 32 + quad * 8 + 4]; \
            float pf[8] = {p0.x, p0.y, p0.z, p0.w, p1.x, p1.y, p1.z, p1.w};    \
            f16x8 ph8, pl8;                                                    \
            _Pragma("unroll") for (int ii = 0; ii < 8; ++ii) {                 \
                f16 hh, ll; split16(pf[ii], hh, ll); ph8[ii] = hh; pl8[ii] = ll; } \
            __builtin_amdgcn_s_setprio(1);                                     \
            _Pragma("unroll") for (int j = 0; j < 4; ++j) {                    \
                int ro = (R) + ks * 2048 + (j * 16 + c) * 32 + qsw_a * 8;      \
                f16x8 vh8 = *(const f16x8*)&pool[ro];                          \
                f16x8 vl8 = *(const f16x8*)&pool[ro + 4096];                   \
                o[j] = __builtin_amdgcn_mfma_f32_16x16x32_f16(ph8, vh8, o[j], 0, 0, 0); \
                o[j] = __builtin_amdgcn_mfma_f32_16x16x32_f16(ph8, vl8, o[j], 0, 0, 0); \
                o[j] = __builtin_amdgcn_mfma_f32_16x16x32_f16(pl8, vh8, o[j], 0, 0, 0); \
            }                                                                  \
            __builtin_amdgcn_s_setprio(0);                                     \
        } } while (0)

    // vt = 0
    SPS_WRITE(0);
    WAIT_VMLG(8); BAR();       // VT0 done, sPs(0) visible; VT1/VT2 in flight
    PV_TILE(R0, 2);

    // vt = 1
    WAIT_LG(); BAR();          // all reads of sPs(0)/VT0 done
    VT_ISSUE(R0, 3);
    SPS_WRITE(1);
    WAIT_VMLG(8); BAR();       // VT1 done; VT2/VT3 in flight
    PV_TILE(R1, 2);

    // vt = 2
    WAIT_LG(); BAR();
    SPS_WRITE(2);
    WAIT_VMLG(4); BAR();       // VT2 done; VT3 in flight
    PV_TILE(R2, 2);

    // vt = 3 (only ks=0 holds live keys 192..196)
    WAIT_LG(); BAR();
    SPS_WRITE(3);
    WAIT_VMLG(0); BAR();       // VT3 done
    PV_TILE(R0, 1);

#pragma unroll
    for (int r = 0; r < 4; ++r) {
        int gq = q0 + wq0 + quad * 4 + r;
        if (gq >= TQ) continue;
        float inv = inv_r[r];
#pragma unroll
        for (int j = 0; j < 4; ++j) {
            float v = o[j][r] * inv;
            f16 hh, ll;
            split16(v, hh, ll);
            size_t off = (size_t)(b * TQ + gq) * C_DIM + h * HD + j * 16 + c;
            Oh[off] = hh;
            Ol[off] = ll;
        }
    }
#undef K_ISSUE
#undef VT_ISSUE
#undef QK_TILE
#undef PV_TILE
#undef SPS_WRITE
#undef WAIT_VM
#undef WAIT_VMLG
#undef WAIT_LG
#undef BAR
}

extern "C" void kernel_launch(void* const* d_in, const int* in_sizes, int n_in,
                              void* d_out, int out_size, void* d_ws, size_t ws_size,
                              hipStream_t stream) {
    const float* x       = (const float*)d_in[0];
    const float* conv_w  = (const float*)d_in[1];
    const float* bn_g    = (const float*)d_in[2];
    const float* bn_b    = (const float*)d_in[3];
    const float* bn_m    = (const float*)d_in[4];
    const float* bn_v    = (const float*)d_in[5];
    const float* w_q     = (const float*)d_in[6];
    const float* w_k     = (const float*)d_in[7];
    const float* w_v     = (const float*)d_in[8];
    const float* w_proj  = (const float*)d_in[9];
    const float* b_proj  = (const float*)d_in[10];
    float* out = (float*)d_out;

    const size_t QSZ   = (size_t)QROWS_P * 384 * sizeof(f16);
    const size_t KVSZ  = (size_t)KVROWS_P * 384 * sizeof(f16);
    const size_t WSZ   = 4 * (size_t)WELEM * sizeof(f16);
    const size_t VTSZ  = (size_t)B_SZ * 384 * VT_LD * sizeof(f16);
    const size_t WALLS = 3 * 3840 * sizeof(float);

    char* p = (char*)d_ws;
    f16* qh  = (f16*)p; p += QSZ;
    f16* ql  = (f16*)p; p += QSZ;
    f16* vh  = (f16*)p; p += KVSZ;
    f16* vl  = (f16*)p; p += KVSZ;
    f16* kh  = (f16*)p; p += KVSZ;
    f16* kl  = (f16*)p; p += KVSZ;
    f16* Wh  = (f16*)p; p += WSZ;
    f16* Wl  = (f16*)p; p += WSZ;
    f16* Qph = (f16*)p; p += QSZ;
    f16* Qpl = (f16*)p; p += QSZ;
    f16* Kph = (f16*)p; p += KVSZ;
    f16* Kpl = (f16*)p; p += KVSZ;
    float* wAll = (float*)p; p += WALLS;

    size_t used = (size_t)(p - (char*)d_ws);
    bool sepVT = (ws_size >= used + 2 * VTSZ);
    f16 *VTh, *VTl;
    if (sepVT) {
        VTh = (f16*)p;
        VTl = VTh + (size_t)B_SZ * 384 * VT_LD;
    } else {
        VTh = kh;
        VTl = VTh + (size_t)B_SZ * 384 * VT_LD;
    }
    f16* oh = qh;
    f16* ol = ql;

    // 1) prep
    {
        int total = 4 * WELEM + 3 * C_DIM;
        prep_kernel<<<(total + 255) / 256, 256, 0, stream>>>(
            w_q, w_k, w_v, w_proj, conv_w, bn_g, bn_b, bn_m, bn_v, Wh, Wl, wAll);
    }

    // 2) fused conv (Q + K + V + cls)
    {
        dim3 gc(H_IN + 1, B_SZ);
        fused_conv_kernel<<<gc, 256, 0, stream>>>(x, wAll, qh, ql, kh, kl, vh, vl);
    }

    // 3) projections (swizzled 1-D grids; blocks = ceil(yMax/8)*16)
    if (sepVT) {
        int yMax = QT384 + 2 * KVT384;             // 100
        int nb = ((yMax + 7) / 8) * 16;            // 208
        qkv_proj_kernel<<<nb, 512, 0, stream>>>(qh, ql, kh, kl, vh, vl, Wh, Wl,
                                                Qph, Qpl, Kph, Kpl, VTh, VTl, yMax);
    } else {
        int yMax = QT384 + KVT384;                 // 83
        int nb = ((yMax + 7) / 8) * 16;            // 176
        qkv_proj_kernel<<<nb, 512, 0, stream>>>(qh, ql, kh, kl, vh, vl, Wh, Wl,
                                                Qph, Qpl, Kph, Kpl, VTh, VTl, yMax);
        int nbv = ((KVT384 + 7) / 8) * 16;         // 48
        v_proj_kernel<<<nbv, 512, 0, stream>>>(vh, vl, Wh + 2 * WELEM, Wl + 2 * WELEM,
                                               VTh, VTl);
    }

    // 4) MFMA attention v5 -> oh/ol
    {
        dim3 ga((TQ + 63) / 64, NH, B_SZ);
        attn_mfma5<<<ga, 256, 0, stream>>>(Qph, Qpl, Kph, Kpl, VTh, VTl, oh, ol);
    }

    // 5) output projection + bias -> f32 out
    {
        int nb = ((QT384 + 7) / 8) * 16;           // 144
        out_proj_kernel<<<nb, 512, 0, stream>>>(oh, ol, Wh + 3 * WELEM, Wl + 3 * WELEM,
                                                b_proj, out);
    }
}

// Round 3
// 303.509 us; speedup vs baseline: 1.1278x; 1.1278x over previous
//
#include <hip/hip_runtime.h>
#include <math.h>

#define B_SZ   32
#define C_DIM  384
#define H_IN   28
#define W_IN   28
#define TQ     785   // 1 + 28*28
#define TKV    197   // 1 + 14*14
#define NH     6
#define HD     64
#define SCALE_F 0.05103103630798287f       // 384^-0.5
#define SCALE_L2E (0.05103103630798287f * 1.4426950408889634f)  // fold log2(e)
#define BN_EPS_F 1e-5f

#define QROWS    25120        // B_SZ*TQ
#define KVROWS   6304         // B_SZ*TKV
#define QROWS_P  25344        // 198*128 (pad to BM=128)
#define KVROWS_P 6528         // 51*128
#define WELEM    147456       // 384*384
#define VT_LD    208          // V^T key stride (16B-aligned rows, >= 197)

#define QT128    198          // 128-row M-tiles for Q rows
#define KVT128   51           // 128-row M-tiles for K/V rows

typedef _Float16 f16;
typedef f16  f16x8 __attribute__((ext_vector_type(8)));
typedef f16  f16x4 __attribute__((ext_vector_type(4)));
typedef float f32x4 __attribute__((ext_vector_type(4)));

__device__ __forceinline__ void split16(float v, f16& h, f16& l) {
    h = (f16)v;
    l = (f16)(v - (float)h);
}

// async global->LDS DMA, 16 B per lane. HW writes at wave-uniform base +
// lane*16 -- every call site computes LDS offset == uniform + lane*16 B.
__device__ __forceinline__ void cp16(void* lds, const void* g) {
    __builtin_amdgcn_global_load_lds(
        (const __attribute__((address_space(1))) unsigned int*)g,
        (__attribute__((address_space(3))) unsigned int*)lds, 16, 0, 0);
}

// XCD-sibling swizzle: 24-block groups; the 3 n0-siblings of one y-tile sit at
// ids {g*24+xcd, +8, +16} -> same XCD under round-robin id%8 placement, so the
// shared A-panel is L2-local. Returns false for pad blocks.
__device__ __forceinline__ bool swz(int id, int yMax, int& y, int& n0) {
    int g = id / 24, w = id - g * 24;
    y = g * 8 + (w & 7);
    n0 = (w >> 3) * 128;
    return y < yMax;
}

// ---------------- prep: weight decompose (+scale fold into w_q) + conv/BN fold --
__global__ __launch_bounds__(256) void prep_kernel(
    const float* __restrict__ wq, const float* __restrict__ wk,
    const float* __restrict__ wv, const float* __restrict__ wp,
    const float* __restrict__ conv_w,
    const float* __restrict__ gamma, const float* __restrict__ beta,
    const float* __restrict__ mean, const float* __restrict__ var,
    f16* __restrict__ Wh, f16* __restrict__ Wl,
    float* __restrict__ wAll)
{
    int idx = blockIdx.x * 256 + threadIdx.x;
    if (idx < 4 * WELEM) {
        int which = idx / WELEM, rem = idx - which * WELEM;
        const float* s = (which == 0) ? wq : (which == 1) ? wk : (which == 2) ? wv : wp;
        float v = s[rem];
        if (which == 0) v *= SCALE_L2E;   // QK^T logits in log2 domain
        f16 h, l;
        split16(v, h, l);
        Wh[idx] = h; Wl[idx] = l;
    } else if (idx < 4 * WELEM + 3 * C_DIM) {
        int k = idx - 4 * WELEM;
        int cv = k / C_DIM, c = k - cv * C_DIM;
        float inv = gamma[k] * rsqrtf(var[k] + BN_EPS_F);
#pragma unroll
        for (int t = 0; t < 9; ++t)
            wAll[cv * 3840 + t * C_DIM + c] = conv_w[(size_t)cv * C_DIM * 9 + c * 9 + t] * inv;
        wAll[cv * 3840 + 9 * C_DIM + c] = beta[k] - mean[k] * inv;
    }
}

// ---------------- fused depthwise conv (Q stride1 + K/V stride2) + cls row -----
__global__ __launch_bounds__(256) void fused_conv_kernel(
    const float* __restrict__ x,
    const float* __restrict__ wAll,
    f16* __restrict__ qh, f16* __restrict__ ql,
    f16* __restrict__ kh, f16* __restrict__ kl,
    f16* __restrict__ vh, f16* __restrict__ vl)
{
    __shared__ float sW[3 * 3840];
    int tid = threadIdx.x;
    int oi = blockIdx.x, b = blockIdx.y;

    if (oi == H_IN) {                 // cls-token path
        if (tid < 96) {
            int c = tid * 4;
            float4 v = *(const float4*)&x[(size_t)b * TQ * C_DIM + c];
            float a[4] = {v.x, v.y, v.z, v.w};
            f16x4 hv, lv;
#pragma unroll
            for (int u = 0; u < 4; ++u) { f16 h, l; split16(a[u], h, l); hv[u] = h; lv[u] = l; }
            size_t oq = (size_t)b * TQ * C_DIM + c;
            size_t okv = (size_t)b * TKV * C_DIM + c;
            *(f16x4*)&qh[oq] = hv;  *(f16x4*)&ql[oq] = lv;
            *(f16x4*)&kh[okv] = hv; *(f16x4*)&kl[okv] = lv;
            *(f16x4*)&vh[okv] = hv; *(f16x4*)&vl[okv] = lv;
        }
        return;
    }

#pragma unroll
    for (int i = 0; i < 12; ++i) {
        int idx = tid + 256 * i;
        if (idx < 2880) cp16(&sW[idx * 4], &wAll[idx * 4]);
    }
    __syncthreads();

    const size_t xb = (size_t)b * TQ * C_DIM + C_DIM;
    bool oi_even = (oi & 1) == 0;

    for (int it = 0; it < 11; ++it) {
        int idx = tid + 256 * it;
        if (idx >= 28 * 96) break;
        int oj = idx / 96, cg = idx - oj * 96;
        int c = cg * 4;

        float4 xv[9];
#pragma unroll
        for (int di = 0; di < 3; ++di) {
            int ii = oi + di - 1;
            bool rok = (ii >= 0) && (ii < H_IN);
#pragma unroll
            for (int dj = 0; dj < 3; ++dj) {
                int jj = oj + dj - 1;
                bool ok = rok && (jj >= 0) && (jj < W_IN);
                xv[di * 3 + dj] = ok ? *(const float4*)&x[xb + ((size_t)ii * W_IN + jj) * C_DIM + c]
                                     : make_float4(0.f, 0.f, 0.f, 0.f);
            }
        }

        {
            float4 acc = *(const float4*)&sW[0 * 3840 + 9 * C_DIM + c];
#pragma unroll
            for (int t = 0; t < 9; ++t) {
                float4 w4 = *(const float4*)&sW[0 * 3840 + t * C_DIM + c];
                acc.x += w4.x * xv[t].x; acc.y += w4.y * xv[t].y;
                acc.z += w4.z * xv[t].z; acc.w += w4.w * xv[t].w;
            }
            f16x4 hv, lv;
            float a[4] = {acc.x, acc.y, acc.z, acc.w};
#pragma unroll
            for (int u = 0; u < 4; ++u) { f16 h, l; split16(a[u], h, l); hv[u] = h; lv[u] = l; }
            size_t off = ((size_t)b * TQ + 1 + oi * W_IN + oj) * C_DIM + c;
            *(f16x4*)&qh[off] = hv;
            *(f16x4*)&ql[off] = lv;
        }

        if (oi_even && ((oj & 1) == 0)) {
            int p = (oi >> 1) * 14 + (oj >> 1);
            size_t off = ((size_t)b * TKV + 1 + p) * C_DIM + c;
#pragma unroll
            for (int cv = 1; cv <= 2; ++cv) {
                float4 acc = *(const float4*)&sW[cv * 3840 + 9 * C_DIM + c];
#pragma unroll
                for (int t = 0; t < 9; ++t) {
                    float4 w4 = *(const float4*)&sW[cv * 3840 + t * C_DIM + c];
                    acc.x += w4.x * xv[t].x; acc.y += w4.y * xv[t].y;
                    acc.z += w4.z * xv[t].z; acc.w += w4.w * xv[t].w;
                }
                f16x4 hv, lv;
                float a[4] = {acc.x, acc.y, acc.z, acc.w};
#pragma unroll
                for (int u = 0; u < 4; ++u) { f16 h, l; split16(a[u], h, l); hv[u] = h; lv[u] = l; }
                if (cv == 1) { *(f16x4*)&kh[off] = hv; *(f16x4*)&kl[off] = lv; }
                else         { *(f16x4*)&vh[off] = hv; *(f16x4*)&vl[off] = lv; }
            }
        }
    }
}

// ---------------- split-f16 MFMA GEMM body v4 ---------------------------------
// 128x128 tile, BK=32, 256 threads (4 waves, per-wave 64x64, acc[4][4] = 64 VGPR
// -- NO spill, R2's acc[6][6] spilled at VGPR=128). Asymmetric buffering to hit
// 2 blocks/CU at depth-2 A-prefetch: A triple-buffered (3x16KB), B double-
// buffered (2x16KB) = 80 KB exactly -> 2 independent blocks/CU (160 KB).
// Counted waits: issue order per step k is [B(k+1), A(k+2)], so the per-wave
// vmcnt FIFO at step k's wait is [A(k), B(k), A(k+1)] -> wait vmcnt(4) leaves
// A(k+1) in flight. Only k=11 drains. Safety of one barrier/step: buffer being
// overwritten was ds_read two steps (A) / one step (B) ago, and every wave
// drains lgkmcnt(0) before its MFMA cluster, hence before the next barrier.
// T2 chunk swizzle: source pre-swizzle (idx&3)^((row>>1)&3), read qsw.
__device__ __forceinline__ void gemm_body(
    const f16* __restrict__ Ah, const f16* __restrict__ Al,
    const f16* __restrict__ Wh, const f16* __restrict__ Wl,
    const float* __restrict__ bias,
    float* __restrict__ Cf, f16* __restrict__ Coh, f16* __restrict__ Col,
    int M, int mode, int m0, int n0)
{
    __shared__ f16 sA[3][8192];   // [abuf][ Ah 128x32 | Al 128x32 ]
    __shared__ f16 sB[2][8192];   // [bbuf][ Bh 128x32 | Bl 128x32 ]

    const int t = threadIdx.x;
    const int wv = t >> 6, lane = t & 63;
    const int wr = (wv >> 1) * 64;    // wave M offset
    const int wc = (wv & 1) * 64;     // wave N offset
    const int lrow = lane & 15, quad = lane >> 4;
    const int qsw = quad ^ ((lrow >> 1) & 3);   // T2 read-side chunk swizzle

    // staging: idx = t (+256), row = idx>>2 (0..127), lds chunk = idx&3,
    // global chunk = (idx&3)^((row>>1)&3); note (t+256) gives same g, row+64.
    const int r0 = t >> 2;
    const int g0 = (t & 3) ^ ((t >> 3) & 3);

    const f16* pAh = Ah + (size_t)(m0 + r0) * 384 + g0 * 8;
    const f16* pAl = Al + (size_t)(m0 + r0) * 384 + g0 * 8;
    const f16* pBh = Wh + (size_t)(n0 + r0) * 384 + g0 * 8;
    const f16* pBl = Wl + (size_t)(n0 + r0) * 384 + g0 * 8;

#define ISSUE_A(ab, kk) do {                                  \
        f16* d = &sA[ab][t * 8];                              \
        const int ko = (kk) * 32;                             \
        cp16(d,        pAh + ko);                             \
        cp16(d + 2048, pAh + 64 * 384 + ko);                  \
        cp16(d + 4096, pAl + ko);                             \
        cp16(d + 6144, pAl + 64 * 384 + ko);                  \
    } while (0)
#define ISSUE_B(bb, kk) do {                                  \
        f16* d = &sB[bb][t * 8];                              \
        const int ko = (kk) * 32;                             \
        cp16(d,        pBh + ko);                             \
        cp16(d + 2048, pBh + 64 * 384 + ko);                  \
        cp16(d + 4096, pBl + ko);                             \
        cp16(d + 6144, pBl + 64 * 384 + ko);                  \
    } while (0)

    f32x4 acc[4][4];
#pragma unroll
    for (int i = 0; i < 4; ++i)
#pragma unroll
        for (int j = 0; j < 4; ++j)
            acc[i][j] = (f32x4){0.f, 0.f, 0.f, 0.f};

    // prologue: two K-steps in flight (queue: B0 A0 B1 A1)
    ISSUE_B(0, 0); ISSUE_A(0, 0);
    ISSUE_B(1, 1); ISSUE_A(1, 1);

#pragma unroll
    for (int kk = 0; kk < 12; ++kk) {
        if (kk == 0)       asm volatile("s_waitcnt vmcnt(8)" ::: "memory");
        else if (kk == 11) asm volatile("s_waitcnt vmcnt(0)" ::: "memory");
        else               asm volatile("s_waitcnt vmcnt(4)" ::: "memory");
        __builtin_amdgcn_s_barrier();
        __builtin_amdgcn_sched_barrier(0);

        // issue next tiles (B before A keeps the FIFO arithmetic exact)
        if (kk >= 1 && kk <= 10) ISSUE_B((kk + 1) & 1, kk + 1);
        if (kk <= 9)             ISSUE_A((kk + 2) % 3, kk + 2);
        __builtin_amdgcn_sched_barrier(0);

        const f16* pa = sA[kk % 3];
        const f16* pb = sB[kk & 1];
        f16x8 ah[4], al[4], bh[4], bl[4];
#pragma unroll
        for (int j = 0; j < 4; ++j) {
            int ro = (wc + j * 16 + lrow) * 32 + qsw * 8;
            bh[j] = *(const f16x8*)&pb[ro];
            bl[j] = *(const f16x8*)&pb[4096 + ro];
        }
#pragma unroll
        for (int i = 0; i < 4; ++i) {
            int ro = (wr + i * 16 + lrow) * 32 + qsw * 8;
            ah[i] = *(const f16x8*)&pa[ro];
            al[i] = *(const f16x8*)&pa[4096 + ro];
        }
        asm volatile("s_waitcnt lgkmcnt(0)" ::: "memory");
        __builtin_amdgcn_sched_barrier(0);     // rule #18: pin MFMAs below wait

        __builtin_amdgcn_s_setprio(1);
#pragma unroll
        for (int i = 0; i < 4; ++i)
#pragma unroll
            for (int j = 0; j < 4; ++j) {
                acc[i][j] = __builtin_amdgcn_mfma_f32_16x16x32_f16(ah[i], bh[j], acc[i][j], 0, 0, 0);
                acc[i][j] = __builtin_amdgcn_mfma_f32_16x16x32_f16(ah[i], bl[j], acc[i][j], 0, 0, 0);
                acc[i][j] = __builtin_amdgcn_mfma_f32_16x16x32_f16(al[i], bh[j], acc[i][j], 0, 0, 0);
            }
        __builtin_amdgcn_s_setprio(0);
    }
#undef ISSUE_A
#undef ISSUE_B

    // epilogue: C/D layout col=lane&15, row=quad*4+reg
#pragma unroll
    for (int i = 0; i < 4; ++i) {
        int grow0 = m0 + wr + i * 16 + quad * 4;
#pragma unroll
        for (int j = 0; j < 4; ++j) {
            int gcol = n0 + wc + j * 16 + lrow;
            float bb = (bias && mode == 0) ? bias[gcol] : 0.f;
#pragma unroll
            for (int r = 0; r < 4; ++r) {
                int grow = grow0 + r;
                if (grow >= M) continue;
                float v = acc[i][j][r] + bb;
                if (mode == 0) {
                    Cf[(size_t)grow * 384 + gcol] = v;
                } else if (mode == 1) {
                    f16 h, l;
                    split16(v, h, l);
                    Coh[(size_t)grow * 384 + gcol] = h;
                    Col[(size_t)grow * 384 + gcol] = l;
                } else {
                    int bb2 = grow / TKV;
                    int key = grow - bb2 * TKV;
                    size_t off = (size_t)bb2 * 384 * VT_LD + (size_t)gcol * VT_LD + key;
                    f16 h, l;
                    split16(v, h, l);
                    Coh[off] = h;
                    Col[off] = l;
                }
            }
        }
    }
}

// Q/K/V projections, swizzled 1-D grid. y in [0,198) Q, [198,249) K, [249,300) V.
__global__ __launch_bounds__(256, 2) void qkv_proj_kernel(
    const f16* __restrict__ qh, const f16* __restrict__ ql,
    const f16* __restrict__ kh, const f16* __restrict__ kl,
    const f16* __restrict__ vh, const f16* __restrict__ vl,
    const f16* __restrict__ Wh, const f16* __restrict__ Wl,
    f16* __restrict__ Qph, f16* __restrict__ Qpl,
    f16* __restrict__ Kph, f16* __restrict__ Kpl,
    f16* __restrict__ VTh, f16* __restrict__ VTl,
    int yMax)
{
    int y, n0;
    if (!swz(blockIdx.x, yMax, y, n0)) return;
    if (y < QT128)
        gemm_body(qh, ql, Wh, Wl, nullptr, nullptr, Qph, Qpl, QROWS, 1, y * 128, n0);
    else if (y < QT128 + KVT128)
        gemm_body(kh, kl, Wh + WELEM, Wl + WELEM, nullptr, nullptr, Kph, Kpl,
                  KVROWS, 1, (y - QT128) * 128, n0);
    else
        gemm_body(vh, vl, Wh + 2 * WELEM, Wl + 2 * WELEM, nullptr, nullptr, VTh, VTl,
                  KVROWS, 2, (y - QT128 - KVT128) * 128, n0);
}

// fallback V projection (aliased-VT workspace layout), swizzled
__global__ __launch_bounds__(256, 2) void v_proj_kernel(
    const f16* __restrict__ vh, const f16* __restrict__ vl,
    const f16* __restrict__ Wh, const f16* __restrict__ Wl,
    f16* __restrict__ VTh, f16* __restrict__ VTl)
{
    int y, n0;
    if (!swz(blockIdx.x, KVT128, y, n0)) return;
    gemm_body(vh, vl, Wh, Wl, nullptr, nullptr, VTh, VTl, KVROWS, 2, y * 128, n0);
}

__global__ __launch_bounds__(256, 2) void out_proj_kernel(
    const f16* __restrict__ Ah, const f16* __restrict__ Al,
    const f16* __restrict__ Wh, const f16* __restrict__ Wl,
    const float* __restrict__ bias, float* __restrict__ Cf)
{
    int y, n0;
    if (!swz(blockIdx.x, QT128, y, n0)) return;
    gemm_body(Ah, Al, Wh, Wl, bias, Cf, nullptr, nullptr, QROWS, 0, y * 128, n0);
}

// ---------------- MFMA attention v5: counted-vmcnt pipeline ---------------------
// Raw s_barrier + counted vmcnt everywhere (no full drains). Q in registers.
// LDS: pool = 3 regions x 8192 f16 (R2=Q @0, R0 @8192, R1 @16384) + sPs.
// K tiles: 0->R0 1->R1 2->R0 3->R2 (K2/K3 issued after kt=1's barrier).
// VT tiles: 0->R0 1->R1 2->R2 (issued before softmax), 3->R0 (after PV0).
// T2 chunk swizzle on all f16 tiles. kt=3: j=0 only; vt=3: ks=0 only (rest masked).
__global__ __launch_bounds__(256) void attn_mfma5(
    const f16* __restrict__ Qh, const f16* __restrict__ Ql,
    const f16* __restrict__ Kh, const f16* __restrict__ Kl,
    const f16* __restrict__ VTh, const f16* __restrict__ VTl,
    f16* __restrict__ Oh, f16* __restrict__ Ol)
{
    __shared__ f16 pool[3 * 8192];      // 48 KB
    __shared__ float sPs[64][68];       // 17 KB -> total 66.5 KB, 2 blocks/CU

    const int t = threadIdx.x;
    const int wv = t >> 6, lane = t & 63;
    const int c = lane & 15, quad = lane >> 4;
    const int wq0 = wv * 16;
    const int h = blockIdx.y, b = blockIdx.z;
    const int q0 = blockIdx.x * 64;
    const int qsw_a = quad ^ ((c >> 1) & 3);

    const int R2 = 0, R0 = 8192, R1 = 16384;

    const size_t qbase  = (size_t)b * TQ * C_DIM + h * HD;
    const size_t kbase  = (size_t)b * TKV * C_DIM + h * HD;
    const size_t vtbase = (size_t)b * 384 * VT_LD + (size_t)h * HD * VT_LD;

    // staging: per tile 4 cp16/thread; lane covers row wv*16+(lane>>2),
    // source chunk pre-swizzled with (lane>>3)&3.
    const int srow = wv * 16 + (lane >> 2);
    const int gch  = (lane & 3) ^ ((lane >> 3) & 3);
    const int ldst = wv * 512 + lane * 8;         // f16 units

    const size_t qg = qbase + (size_t)(q0 + srow) * C_DIM + gch * 8;
    const size_t kg = kbase + (size_t)srow * C_DIM + gch * 8;
    const size_t vg = vtbase + (size_t)srow * VT_LD + gch * 8;

#define K_ISSUE(R, KT) do {                                          \
        size_t o_ = kg + (size_t)(KT) * 64 * C_DIM;                  \
        cp16(pool + (R) + ldst,        &Kh[o_]);                     \
        cp16(pool + (R) + 2048 + ldst, &Kh[o_ + 32]);                \
        cp16(pool + (R) + 4096 + ldst, &Kl[o_]);                     \
        cp16(pool + (R) + 6144 + ldst, &Kl[o_ + 32]);                \
    } while (0)

#define VT_ISSUE(R, VT) do {                                         \
        size_t o_ = vg + (VT) * 64;                                  \
        cp16(pool + (R) + ldst,        &VTh[o_]);                    \
        cp16(pool + (R) + 2048 + ldst, &VTh[o_ + 32]);               \
        cp16(pool + (R) + 4096 + ldst, &VTl[o_]);                    \
        cp16(pool + (R) + 6144 + ldst, &VTl[o_ + 32]);               \
    } while (0)

#define WAIT_VM(N)  asm volatile("s_waitcnt vmcnt(" #N ")" ::: "memory")
#define WAIT_VMLG(N) asm volatile("s_waitcnt vmcnt(" #N ") lgkmcnt(0)" ::: "memory")
#define WAIT_LG()   asm volatile("s_waitcnt lgkmcnt(0)" ::: "memory")
#define BAR() do { __builtin_amdgcn_s_barrier(); __builtin_amdgcn_sched_barrier(0); } while (0)

    f32x4 s[4][4];
#pragma unroll
    for (int kt = 0; kt < 4; ++kt)
#pragma unroll
        for (int j = 0; j < 4; ++j)
            s[kt][j] = (f32x4){0.f, 0.f, 0.f, 0.f};

    // prologue: Q -> R2, K0 -> R0, K1 -> R1
    {
        cp16(pool + R2 + ldst,        &Qh[qg]);
        cp16(pool + R2 + 2048 + ldst, &Qh[qg + 32]);
        cp16(pool + R2 + 4096 + ldst, &Ql[qg]);
        cp16(pool + R2 + 6144 + ldst, &Ql[qg + 32]);
    }
    K_ISSUE(R0, 0);
    K_ISSUE(R1, 1);

    f16x8 q8h[2], q8l[2];

#define QK_TILE(KT, R, JMAX) do {                                              \
        __builtin_amdgcn_s_setprio(1);                                         \
        _Pragma("unroll") for (int ks = 0; ks < 2; ++ks) {                     \
            _Pragma("unroll") for (int j = 0; j < (JMAX); ++j) {               \
                int ro = (R) + ks * 2048 + (j * 16 + c) * 32 + qsw_a * 8;      \
                f16x8 kh8 = *(const f16x8*)&pool[ro];                          \
                f16x8 kl8 = *(const f16x8*)&pool[ro + 4096];                   \
                s[KT][j] = __builtin_amdgcn_mfma_f32_16x16x32_f16(q8h[ks], kh8, s[KT][j], 0, 0, 0); \
                s[KT][j] = __builtin_amdgcn_mfma_f32_16x16x32_f16(q8h[ks], kl8, s[KT][j], 0, 0, 0); \
                s[KT][j] = __builtin_amdgcn_mfma_f32_16x16x32_f16(q8l[ks], kh8, s[KT][j], 0, 0, 0); \
            } }                                                                \
        __builtin_amdgcn_s_setprio(0);                                         \
    } while (0)

    // kt = 0 (Q + K0 ready; K1 in flight)
    WAIT_VM(4); BAR();
#pragma unroll
    for (int ks = 0; ks < 2; ++ks) {
        int ro = R2 + ks * 2048 + (wq0 + c) * 32 + qsw_a * 8;
        q8h[ks] = *(const f16x8*)&pool[ro];
        q8l[ks] = *(const f16x8*)&pool[ro + 4096];
    }
    QK_TILE(0, R0, 4);

    // kt = 1
    WAIT_VM(0); BAR();
    K_ISSUE(R0, 2);          // R0's kt=0 reads done (barrier above)
    K_ISSUE(R2, 3);          // Q regs loaded before the barrier
    QK_TILE(1, R1, 4);

    // kt = 2
    WAIT_VM(4); BAR();
    QK_TILE(2, R0, 4);

    // kt = 3 (masked tile: only j=0 holds live keys 192..196)
    WAIT_VM(0); BAR();
    QK_TILE(3, R2, 1);

    // all QK LDS reads done -> regions free for V
    WAIT_LG(); BAR();
    VT_ISSUE(R0, 0);
    VT_ISSUE(R1, 1);
    VT_ISSUE(R2, 2);

    // masking + softmax (rides over VT DMA)
#pragma unroll
    for (int r = 0; r < 4; ++r) {
        s[3][0][r] = (c < 5) ? s[3][0][r] : -1e30f;
        s[3][1][r] = -1e30f;
        s[3][2][r] = -1e30f;
        s[3][3][r] = -1e30f;
    }

    float inv_r[4];
#pragma unroll
    for (int r = 0; r < 4; ++r) {
        float mx = -1e30f;
#pragma unroll
        for (int kt = 0; kt < 4; ++kt)
#pragma unroll
            for (int j = 0; j < 4; ++j)
                mx = fmaxf(mx, s[kt][j][r]);
        mx = fmaxf(mx, __shfl_xor(mx, 1));
        mx = fmaxf(mx, __shfl_xor(mx, 2));
        mx = fmaxf(mx, __shfl_xor(mx, 4));
        mx = fmaxf(mx, __shfl_xor(mx, 8));
        float sum = 0.f;
#pragma unroll
        for (int kt = 0; kt < 4; ++kt)
#pragma unroll
            for (int j = 0; j < 4; ++j) {
                float pv = exp2f(s[kt][j][r] - mx);
                s[kt][j][r] = pv;
                sum += pv;
            }
        sum += __shfl_xor(sum, 1);
        sum += __shfl_xor(sum, 2);
        sum += __shfl_xor(sum, 4);
        sum += __shfl_xor(sum, 8);
        inv_r[r] = 1.f / sum;
    }

    f32x4 o[4];
#pragma unroll
    for (int j = 0; j < 4; ++j) o[j] = (f32x4){0.f, 0.f, 0.f, 0.f};

#define SPS_WRITE(VT) do {                                           \
        _Pragma("unroll") for (int r = 0; r < 4; ++r)                \
            _Pragma("unroll") for (int j = 0; j < 4; ++j)            \
                sPs[wq0 + quad * 4 + r][j * 16 + c] = s[VT][j][r];   \
    } while (0)

#define PV_TILE(R, KSMAX) do {                                                 \
        _Pragma("unroll") for (int ks = 0; ks < (KSMAX); ++ks) {               \
            float4 p0 = *(const float4*)&sPs[wq0 + c][ks * 32 + quad * 8];     \
            float4 p1 = *(const float4*)&sPs[wq0 + c][ks * 32 + quad * 8 + 4]; \
            float pf[8] = {p0.x, p0.y, p0.z, p0.w, p1.x, p1.y, p1.z, p1.w};    \
            f16x8 ph8, pl8;                                                    \
            _Pragma("unroll") for (int ii = 0; ii < 8; ++ii) {                 \
                f16 hh, ll; split16(pf[ii], hh, ll); ph8[ii] = hh; pl8[ii] = ll; } \
            __builtin_amdgcn_s_setprio(1);                                     \
            _Pragma("unroll") for (int j = 0; j < 4; ++j) {                    \
                int ro = (R) + ks * 2048 + (j * 16 + c) * 32 + qsw_a * 8;      \
                f16x8 vh8 = *(const f16x8*)&pool[ro];                          \
                f16x8 vl8 = *(const f16x8*)&pool[ro + 4096];                   \
                o[j] = __builtin_amdgcn_mfma_f32_16x16x32_f16(ph8, vh8, o[j], 0, 0, 0); \
                o[j] = __builtin_amdgcn_mfma_f32_16x16x32_f16(ph8, vl8, o[j], 0, 0, 0); \
                o[j] = __builtin_amdgcn_mfma_f32_16x16x32_f16(pl8, vh8, o[j], 0, 0, 0); \
            }                                                                  \
            __builtin_amdgcn_s_setprio(0);                                     \
        } } while (0)

    // vt = 0
    SPS_WRITE(0);
    WAIT_VMLG(8); BAR();       // VT0 done, sPs(0) visible; VT1/VT2 in flight
    PV_TILE(R0, 2);

    // vt = 1
    WAIT_LG(); BAR();          // all reads of sPs(0)/VT0 done
    VT_ISSUE(R0, 3);
    SPS_WRITE(1);
    WAIT_VMLG(8); BAR();       // VT1 done; VT2/VT3 in flight
    PV_TILE(R1, 2);

    // vt = 2
    WAIT_LG(); BAR();
    SPS_WRITE(2);
    WAIT_VMLG(4); BAR();       // VT2 done; VT3 in flight
    PV_TILE(R2, 2);

    // vt = 3 (only ks=0 holds live keys 192..196)
    WAIT_LG(); BAR();
    SPS_WRITE(3);
    WAIT_VMLG(0); BAR();       // VT3 done
    PV_TILE(R0, 1);

#pragma unroll
    for (int r = 0; r < 4; ++r) {
        int gq = q0 + wq0 + quad * 4 + r;
        if (gq >= TQ) continue;
        float inv = inv_r[r];
#pragma unroll
        for (int j = 0; j < 4; ++j) {
            float v = o[j][r] * inv;
            f16 hh, ll;
            split16(v, hh, ll);
            size_t off = (size_t)(b * TQ + gq) * C_DIM + h * HD + j * 16 + c;
            Oh[off] = hh;
            Ol[off] = ll;
        }
    }
#undef K_ISSUE
#undef VT_ISSUE
#undef QK_TILE
#undef PV_TILE
#undef SPS_WRITE
#undef WAIT_VM
#undef WAIT_VMLG
#undef WAIT_LG
#undef BAR
}

extern "C" void kernel_launch(void* const* d_in, const int* in_sizes, int n_in,
                              void* d_out, int out_size, void* d_ws, size_t ws_size,
                              hipStream_t stream) {
    const float* x       = (const float*)d_in[0];
    const float* conv_w  = (const float*)d_in[1];
    const float* bn_g    = (const float*)d_in[2];
    const float* bn_b    = (const float*)d_in[3];
    const float* bn_m    = (const float*)d_in[4];
    const float* bn_v    = (const float*)d_in[5];
    const float* w_q     = (const float*)d_in[6];
    const float* w_k     = (const float*)d_in[7];
    const float* w_v     = (const float*)d_in[8];
    const float* w_proj  = (const float*)d_in[9];
    const float* b_proj  = (const float*)d_in[10];
    float* out = (float*)d_out;

    const size_t QSZ   = (size_t)QROWS_P * 384 * sizeof(f16);
    const size_t KVSZ  = (size_t)KVROWS_P * 384 * sizeof(f16);
    const size_t WSZ   = 4 * (size_t)WELEM * sizeof(f16);
    const size_t VTSZ  = (size_t)B_SZ * 384 * VT_LD * sizeof(f16);
    const size_t WALLS = 3 * 3840 * sizeof(float);

    char* p = (char*)d_ws;
    f16* qh  = (f16*)p; p += QSZ;
    f16* ql  = (f16*)p; p += QSZ;
    f16* vh  = (f16*)p; p += KVSZ;
    f16* vl  = (f16*)p; p += KVSZ;
    f16* kh  = (f16*)p; p += KVSZ;
    f16* kl  = (f16*)p; p += KVSZ;
    f16* Wh  = (f16*)p; p += WSZ;
    f16* Wl  = (f16*)p; p += WSZ;
    f16* Qph = (f16*)p; p += QSZ;
    f16* Qpl = (f16*)p; p += QSZ;
    f16* Kph = (f16*)p; p += KVSZ;
    f16* Kpl = (f16*)p; p += KVSZ;
    float* wAll = (float*)p; p += WALLS;

    size_t used = (size_t)(p - (char*)d_ws);
    bool sepVT = (ws_size >= used + 2 * VTSZ);
    f16 *VTh, *VTl;
    if (sepVT) {
        VTh = (f16*)p;
        VTl = VTh + (size_t)B_SZ * 384 * VT_LD;
    } else {
        VTh = kh;
        VTl = VTh + (size_t)B_SZ * 384 * VT_LD;
    }
    f16* oh = qh;
    f16* ol = ql;

    // 1) prep
    {
        int total = 4 * WELEM + 3 * C_DIM;
        prep_kernel<<<(total + 255) / 256, 256, 0, stream>>>(
            w_q, w_k, w_v, w_proj, conv_w, bn_g, bn_b, bn_m, bn_v, Wh, Wl, wAll);
    }

    // 2) fused conv (Q + K + V + cls)
    {
        dim3 gc(H_IN + 1, B_SZ);
        fused_conv_kernel<<<gc, 256, 0, stream>>>(x, wAll, qh, ql, kh, kl, vh, vl);
    }

    // 3) projections (swizzled 1-D grids; blocks = ceil(yMax/8)*24)
    if (sepVT) {
        int yMax = QT128 + 2 * KVT128;             // 300
        int nb = ((yMax + 7) / 8) * 24;            // 912
        qkv_proj_kernel<<<nb, 256, 0, stream>>>(qh, ql, kh, kl, vh, vl, Wh, Wl,
                                                Qph, Qpl, Kph, Kpl, VTh, VTl, yMax);
    } else {
        int yMax = QT128 + KVT128;                 // 249
        int nb = ((yMax + 7) / 8) * 24;            // 768
        qkv_proj_kernel<<<nb, 256, 0, stream>>>(qh, ql, kh, kl, vh, vl, Wh, Wl,
                                                Qph, Qpl, Kph, Kpl, VTh, VTl, yMax);
        int nbv = ((KVT128 + 7) / 8) * 24;         // 168
        v_proj_kernel<<<nbv, 256, 0, stream>>>(vh, vl, Wh + 2 * WELEM, Wl + 2 * WELEM,
                                               VTh, VTl);
    }

    // 4) MFMA attention v5 -> oh/ol
    {
        dim3 ga((TQ + 63) / 64, NH, B_SZ);
        attn_mfma5<<<ga, 256, 0, stream>>>(Qph, Qpl, Kph, Kpl, VTh, VTl, oh, ol);
    }

    // 5) output projection + bias -> f32 out
    {
        int nb = ((QT128 + 7) / 8) * 24;           // 600
        out_proj_kernel<<<nb, 256, 0, stream>>>(oh, ol, Wh + 3 * WELEM, Wl + 3 * WELEM,
                                                b_proj, out);
    }
}